// Round 4
// baseline (258.331 us; speedup 1.0000x reference)
//
#include <hip/hip_runtime.h>

// MMD loss, N=4096 per side, D=256, fp32.
// R4: split-bf16 MFMA Gram with ONE-SHOT fp32->(hi,lo) conversion pre-pass
//     (planes in d_ws), 3 MFMA passes (hh+hl+lh; ll dropped, ~2^-18 rel),
//     global_load_lds width=16 staging into granule-major LDS
//     ([granule][row] 16B units -> frag reads 2 lanes/bank = free).
//     128x128 tile, 2x2 waves, 4x4 subtiles of 16x16x32 MFMA each.
//     Bandwidth scale from exact fp32 pre-pass (unchanged semantics).

#define NROWS 8192
#define HALF  4096
#define DIM   256
#define BM    128
#define BK    32          // = MFMA K; 4 granules of 8 bf16 per row

typedef __bf16 bf16x8 __attribute__((ext_vector_type(8)));
typedef float f32x4 __attribute__((ext_vector_type(4)));
typedef unsigned short ushort8 __attribute__((ext_vector_type(8)));

__device__ __forceinline__ const float* row_ptr(const float* src, const float* tgt, int r) {
    return (r < HALF) ? (src + (size_t)r * DIM) : (tgt + (size_t)(r - HALF) * DIM);
}

__device__ __forceinline__ unsigned short bf16_rne(float x) {
    unsigned int u = __builtin_bit_cast(unsigned int, x);
    return (unsigned short)((u + 0x7FFFu + ((u >> 16) & 1u)) >> 16);
}

__device__ __forceinline__ void gl2lds16(const void* g, void* l) {
    __builtin_amdgcn_global_load_lds(
        (const __attribute__((address_space(1))) unsigned int*)g,
        (__attribute__((address_space(3))) unsigned int*)l, 16, 0, 0);
}

// --- Phase 0: fp32 -> hi/lo bf16 planes + sq[i]; block 0 zeroes colsum/accum ---
__global__ __launch_bounds__(256) void k_conv(const float* __restrict__ src,
                                              const float* __restrict__ tgt,
                                              unsigned short* __restrict__ hi,
                                              unsigned short* __restrict__ lo,
                                              float* __restrict__ sq,
                                              float* __restrict__ colsum,
                                              double* __restrict__ accum) {
    int wave = threadIdx.x >> 6;
    int lane = threadIdx.x & 63;
    int row  = blockIdx.x * 4 + wave;
    const float* rp = row_ptr(src, tgt, row);
    float4 v = ((const float4*)rp)[lane];           // 64 lanes * 4 floats = 256
    float xs[4] = {v.x, v.y, v.z, v.w};
    ushort4 h4, l4;
    unsigned short hs[4], ls[4];
    #pragma unroll
    for (int j = 0; j < 4; ++j) {
        unsigned short hh = bf16_rne(xs[j]);
        float hr = __builtin_bit_cast(float, (unsigned int)hh << 16);
        hs[j] = hh;
        ls[j] = bf16_rne(xs[j] - hr);
    }
    h4.x = hs[0]; h4.y = hs[1]; h4.z = hs[2]; h4.w = hs[3];
    l4.x = ls[0]; l4.y = ls[1]; l4.z = ls[2]; l4.w = ls[3];
    ((ushort4*)(hi + (size_t)row * DIM))[lane] = h4;
    ((ushort4*)(lo + (size_t)row * DIM))[lane] = l4;
    float s = v.x * v.x + v.y * v.y + v.z * v.z + v.w * v.w;
    #pragma unroll
    for (int off = 32; off; off >>= 1) s += __shfl_xor(s, off, 64);
    if (lane == 0) sq[row] = s;
    if (blockIdx.x == 0) {
        colsum[threadIdx.x] = 0.0f;
        if (threadIdx.x == 0) *accum = 0.0;
    }
}

// --- Phase 1b: colsum[d] = sum_i total[i][d] (exact fp32) ---
__global__ __launch_bounds__(256) void k_colsum(const float* __restrict__ src,
                                                const float* __restrict__ tgt,
                                                float* __restrict__ colsum) {
    int d  = threadIdx.x;
    int r0 = blockIdx.x * 32;
    float s = 0.0f;
    for (int r = r0; r < r0 + 32; ++r) {
        s += row_ptr(src, tgt, r)[d];               // coalesced across threads
    }
    atomicAdd(&colsum[d], s);
}

// --- Phase 1c: bandwidth -> exp2 scale factor ---
__global__ __launch_bounds__(256) void k_scale(const float* __restrict__ sq,
                                               const float* __restrict__ colsum,
                                               float* __restrict__ scale) {
    __shared__ double sh[256];
    int t = threadIdx.x;
    double s1 = 0.0;
    for (int i = t; i < NROWS; i += 256) s1 += (double)sq[i];
    sh[t] = s1;
    __syncthreads();
    for (int off = 128; off; off >>= 1) {
        if (t < off) sh[t] += sh[t + off];
        __syncthreads();
    }
    double S1 = sh[0];
    __syncthreads();
    double c = (double)colsum[t];
    sh[t] = c * c;
    __syncthreads();
    for (int off = 128; off; off >>= 1) {
        if (t < off) sh[t] += sh[t + off];
        __syncthreads();
    }
    if (t == 0) {
        double S2    = sh[0];
        double n     = (double)NROWS;
        double sumL2 = 2.0 * n * S1 - 2.0 * S2;
        double bw    = sumL2 / (n * n - n) / 4.0;   // / KERNEL_MUL^(KERNEL_NUM//2)
        // u = exp(-L2/(16*bw)) = exp2(scale * L2)
        *scale = (float)(-1.0 / (16.0 * bw * 0.69314718055994530942));
    }
}

// --- Phase 2: split-bf16 MFMA pair-tile kernel, async staging ---
__global__ __launch_bounds__(256, 2) void k_pairs(const unsigned short* __restrict__ hi,
                                                  const unsigned short* __restrict__ lo,
                                                  const float* __restrict__ sq,
                                                  const float* __restrict__ scale_p,
                                                  double* __restrict__ accum) {
    int bi = blockIdx.y, bj = blockIdx.x;
    if (bj < bi) return;                            // upper-triangular tiles only

    // Granule-major: element (row r, granule g of 8 bf16) at ushort offset g*1024 + r*8.
    __shared__ __align__(16) unsigned short AsH[BM * BK];
    __shared__ __align__(16) unsigned short AsL[BM * BK];
    __shared__ __align__(16) unsigned short BsH[BM * BK];
    __shared__ __align__(16) unsigned short BsL[BM * BK];
    __shared__ float wsum[4];

    int t    = threadIdx.x;
    int lane = t & 63;
    int w    = t >> 6;
    int wr   = w >> 1, wc = w & 1;                  // 2x2 wave grid, 64x64 each
    int lr   = lane & 15, lq = lane >> 4;
    int ro = bi * BM, co = bj * BM;

    // Staging: wave w owns one array: 0->A.hi 1->A.lo 2->B.hi 3->B.lo
    const unsigned short* gbase = (w & 1) ? lo : hi;
    int rowoff = (w < 2) ? ro : co;
    const unsigned short* gsrc = gbase + (size_t)rowoff * DIM;
    unsigned short* larr = (w == 0) ? AsH : (w == 1) ? AsL : (w == 2) ? BsH : BsL;

    f32x4 acc[4][4];
    #pragma unroll
    for (int m = 0; m < 4; ++m)
        #pragma unroll
        for (int n = 0; n < 4; ++n) acc[m][n] = (f32x4){0.f, 0.f, 0.f, 0.f};

    #pragma unroll 1
    for (int kk = 0; kk < DIM; kk += BK) {
        __syncthreads();                            // prev frag reads done before overwrite
        #pragma unroll
        for (int g = 0; g < 4; ++g) {
            #pragma unroll
            for (int h = 0; h < 2; ++h) {
                // lane l -> row h*64+l, granule g; LDS dst = base + lane*16 (HW)
                const unsigned short* gp = gsrc + (size_t)(h * 64 + lane) * DIM + kk + g * 8;
                unsigned short* lp = larr + g * 1024 + h * 512;
                gl2lds16(gp, lp);
            }
        }
        __syncthreads();                            // compiler drains vmcnt before barrier

        bf16x8 aH[4], aL[4], bH[4], bL[4];
        #pragma unroll
        for (int m = 0; m < 4; ++m) {
            int ar  = wr * 64 + m * 16 + lr;
            int off = lq * 1024 + ar * 8;
            aH[m] = __builtin_bit_cast(bf16x8, *(const ushort8*)&AsH[off]);
            aL[m] = __builtin_bit_cast(bf16x8, *(const ushort8*)&AsL[off]);
        }
        #pragma unroll
        for (int n = 0; n < 4; ++n) {
            int br  = wc * 64 + n * 16 + lr;
            int off = lq * 1024 + br * 8;
            bH[n] = __builtin_bit_cast(bf16x8, *(const ushort8*)&BsH[off]);
            bL[n] = __builtin_bit_cast(bf16x8, *(const ushort8*)&BsL[off]);
        }
        #pragma unroll
        for (int m = 0; m < 4; ++m)
            #pragma unroll
            for (int n = 0; n < 4; ++n) {
                acc[m][n] = __builtin_amdgcn_mfma_f32_16x16x32_bf16(aH[m], bH[n], acc[m][n], 0, 0, 0);
                acc[m][n] = __builtin_amdgcn_mfma_f32_16x16x32_bf16(aH[m], bL[n], acc[m][n], 0, 0, 0);
                acc[m][n] = __builtin_amdgcn_mfma_f32_16x16x32_bf16(aL[m], bH[n], acc[m][n], 0, 0, 0);
                // lo*lo pass dropped: ~2^-18 relative on Gram term
            }
    }

    // ---- epilogue: L2 -> sum of 5 Gaussian kernels -> reduce
    float scale = *scale_p;
    int ro_eff = ro + wr * 64, co_eff = co + wc * 64;
    float4 sqa4[4];
    float  sqbv[4];
    #pragma unroll
    for (int m = 0; m < 4; ++m) sqa4[m] = *(const float4*)&sq[ro_eff + m * 16 + lq * 4];
    #pragma unroll
    for (int n = 0; n < 4; ++n) sqbv[n] = sq[co_eff + n * 16 + lr];

    float tsum = 0.0f;
    #pragma unroll
    for (int m = 0; m < 4; ++m) {
        float sa[4] = {sqa4[m].x, sqa4[m].y, sqa4[m].z, sqa4[m].w};
        #pragma unroll
        for (int n = 0; n < 4; ++n) {
            #pragma unroll
            for (int r = 0; r < 4; ++r) {
                float L2  = sa[r] + sqbv[n] - 2.0f * acc[m][n][r];
                float u   = __builtin_amdgcn_exp2f(scale * L2);
                float u2  = u * u;
                float u4  = u2 * u2;
                float u8  = u4 * u4;
                float u16 = u8 * u8;
                tsum += u + u2 + u4 + u8 + u16;     // 5 kernel scales
            }
        }
    }

    #pragma unroll
    for (int off = 32; off; off >>= 1) tsum += __shfl_xor(tsum, off, 64);
    if (lane == 0) wsum[w] = tsum;
    __syncthreads();
    if (t == 0) {
        float tot = wsum[0] + wsum[1] + wsum[2] + wsum[3];
        float sgn = ((ro < HALF) == (co < HALF)) ? 1.0f : -1.0f;
        float wgt = (bi == bj) ? 1.0f : 2.0f;       // off-diag tiles stand for (i,j)+(j,i)
        atomicAdd(accum, (double)(sgn * wgt * tot));
    }
}

// --- Finalize: mean normalization ---
__global__ void k_fin(const double* __restrict__ accum, float* __restrict__ out) {
    out[0] = (float)(*accum / ((double)HALF * (double)HALF));
}

extern "C" void kernel_launch(void* const* d_in, const int* in_sizes, int n_in,
                              void* d_out, int out_size, void* d_ws, size_t ws_size,
                              hipStream_t stream) {
    const float* src = (const float*)d_in[0];
    const float* tgt = (const float*)d_in[1];
    float* out = (float*)d_out;

    char* ws = (char*)d_ws;
    double* accum  = (double*)ws;                        // 8 B
    float*  scale  = (float*)(ws + 8);                   // 4 B
    float*  sq     = (float*)(ws + 256);                 // 8192 floats
    float*  colsum = (float*)(ws + 256 + NROWS * 4);     // 256 floats
    unsigned short* hi = (unsigned short*)(ws + 65536);            // 4 MB
    unsigned short* lo = (unsigned short*)(ws + 65536 + (size_t)NROWS * DIM * 2);

    k_conv  <<<NROWS / 4, 256, 0, stream>>>(src, tgt, hi, lo, sq, colsum, accum);
    k_colsum<<<NROWS / 32, 256, 0, stream>>>(src, tgt, colsum);
    k_scale <<<1, 256, 0, stream>>>(sq, colsum, scale);
    k_pairs <<<dim3(NROWS / BM, NROWS / BM), 256, 0, stream>>>(hi, lo, sq, scale, accum);
    k_fin   <<<1, 1, 0, stream>>>(accum, out);
}